// Round 12
// baseline (54.175 us; speedup 1.0000x reference)
//
#include <hip/hip_runtime.h>
#include <hip/hip_bf16.h>

#define NCLASS 19
#define BINS 512
#define NB (NCLASS * BINS)  // 9728 bins
#define NREP 4
#define RPAD 8              // words; shifts each replica's bank phase by 8
#define RSTRIDE (NB + RPAD)
#define IGNORE_IDX (-100)
#define HW_SHIFT 18  // 512*512 = 2^18 (fixed problem shape)
#define HW_C (1 << HW_SHIFT)

#define UNPACK(v)                                            \
  (((unsigned long long)((v) >> 16) << 32) |                 \
   (unsigned long long)((v) & 0xffffu))

// Load one 2-pixel set: 19 float2 logit streams + int2 labels.
#define LOADSET(V, LB, PIX)                                                  \
  {                                                                          \
    int n_ = (PIX) >> HW_SHIFT;                                              \
    int hw_ = (PIX) & (HW_C - 1);                                            \
    const float* lp_ =                                                       \
        logits + (((size_t)n_ * NCLASS) << HW_SHIFT) + hw_;                  \
    _Pragma("unroll") for (int c_ = 0; c_ < NCLASS; ++c_) {                  \
      float2 q_ = *(const float2*)(lp_ + ((size_t)c_ << HW_SHIFT));          \
      V[c_][0] = q_.x;                                                       \
      V[c_][1] = q_.y;                                                       \
    }                                                                        \
    LB = *(const int2*)(labels + (PIX));                                     \
  }

// Softmax + 2x19 histogram atomics for one 2-pixel set.
#define PROCSET(V, LB)                                                       \
  {                                                                          \
    float m0_ = -3.4e38f, m1_ = -3.4e38f;                                    \
    _Pragma("unroll") for (int c_ = 0; c_ < NCLASS; ++c_) {                  \
      m0_ = fmaxf(m0_, V[c_][0]);                                            \
      m1_ = fmaxf(m1_, V[c_][1]);                                            \
    }                                                                        \
    float s0_ = 0.f, s1_ = 0.f;                                              \
    _Pragma("unroll") for (int c_ = 0; c_ < NCLASS; ++c_) {                  \
      V[c_][0] = __expf(V[c_][0] - m0_); s0_ += V[c_][0];                    \
      V[c_][1] = __expf(V[c_][1] - m1_); s1_ += V[c_][1];                    \
    }                                                                        \
    float i0_ = 1.0f / s0_, i1_ = 1.0f / s1_;                                \
    int l0_ = LB.x, l1_ = LB.y;                                              \
    _Pragma("unroll") for (int c_ = 0; c_ < NCLASS; ++c_) {                  \
      if (l0_ != IGNORE_IDX) {                                               \
        float pr_ = V[c_][0] * i0_;                                          \
        bool pos_ = (c_ == l0_);                                             \
        float e_ = pos_ ? (1.0f - pr_) : pr_;                                \
        int b_ = min(BINS - 1, (int)(e_ * (float)BINS));                     \
        atomicAdd(&sh[rep + (c_ << 9) + b_], pos_ ? 0x10000u : 1u);          \
      }                                                                      \
      if (l1_ != IGNORE_IDX) {                                               \
        float pr_ = V[c_][1] * i1_;                                          \
        bool pos_ = (c_ == l1_);                                             \
        float e_ = pos_ ? (1.0f - pr_) : pr_;                                \
        int b_ = min(BINS - 1, (int)(e_ * (float)BINS));                     \
        atomicAdd(&sh[rep + (c_ << 9) + b_], pos_ ? 0x10000u : 1u);          \
      }                                                                      \
    }                                                                        \
  }

// ---------------------------------------------------------------------------
// Phase 1 (proven R7/R8 core, VERBATIM — ~31 us ~= 92% of its HBM floor):
// 2 px/thread float2 loads, 4-way lane-replicated LDS histogram (u32-packed
// pos<<16|neg), register double-buffer prefetch with named A/B sets.
// ---------------------------------------------------------------------------
__global__ void __launch_bounds__(1024, 4) hist_pf(
    const float* __restrict__ logits, const int* __restrict__ labels,
    unsigned* __restrict__ copies, int P, int ppb) {
  extern __shared__ unsigned sh[];  // NREP*RSTRIDE words ~= 152 KB
  for (int i = threadIdx.x; i < NREP * RSTRIDE; i += 1024) sh[i] = 0u;
  __syncthreads();

  const int rep = (threadIdx.x & 3) * RSTRIDE;
  const int STEP = 1024 * 2;
  int p1 = min(P, blockIdx.x * ppb + ppb);
  int p = blockIdx.x * ppb + (int)threadIdx.x * 2;

  float va[NCLASS][2], vb[NCLASS][2];
  int2 la, lb;
  bool has = p < p1;
  if (has) LOADSET(va, la, p);
  while (has) {
    int pn = p + STEP;
    bool hasn = pn < p1;
    if (hasn) LOADSET(vb, lb, pn);  // prefetch next set
    PROCSET(va, la);
    p = pn;
    has = hasn;
    if (!has) break;
    pn = p + STEP;
    hasn = pn < p1;
    if (hasn) LOADSET(va, la, pn);  // prefetch next set
    PROCSET(vb, lb);
    p = pn;
    has = hasn;
  }
  __syncthreads();

  unsigned* dst = copies + (size_t)blockIdx.x * NB;
  for (int i = threadIdx.x; i < NB; i += 1024)
    dst[i] =
        sh[i] + sh[RSTRIDE + i] + sh[2 * RSTRIDE + i] + sh[3 * RSTRIDE + i];
}

// ---------------------------------------------------------------------------
// Phase 2: direct fold + scan, one block per class, 1024 threads = 8 slices
// x 128 quad-threads. Thread (s,q) folds copies r==s (mod 8) for bins
// [4q..4q+3] with ONE uint4 load per copy (16 B/lane, 1 KB/wave/instr, all
// iterations independent -> deep pipelining; 4x the in-flight bytes of R11).
// Slices combine via 32 KB LDS (read side 2-way = free). Then the 512-wide
// Hillis-Steele inclusive suffix scan and Lovasz J accumulation:
// loss_c = (1/BINS)*sum_{b>=1} J_b, (CP,CN) = inclusive suffix counts at b;
// nPos = suffix at bin 0 = class total.
// ---------------------------------------------------------------------------
__global__ void __launch_bounds__(1024) scan19_v2(
    const unsigned* __restrict__ copies, float* __restrict__ partial, int R) {
  int c = blockIdx.x;
  __shared__ unsigned long long sl[8][BINS];  // 32 KB
  __shared__ float fsum[16];
  int tid = threadIdx.x;
  int q = tid & 127;   // quad index: bins [4q .. 4q+3]
  int s = tid >> 7;    // slice 0..7
  int b0 = q << 2;

  // ---- fold: sum copies r = s, s+8, ... for 4 bins via uint4 ----
  unsigned long long A0 = 0, A1 = 0, A2 = 0, A3 = 0;
  const unsigned* cb = copies + (c << 9) + b0;
  for (int r = s; r < R; r += 8) {
    uint4 v = *(const uint4*)(cb + (size_t)r * NB);
    A0 += UNPACK(v.x);
    A1 += UNPACK(v.y);
    A2 += UNPACK(v.z);
    A3 += UNPACK(v.w);
  }
  sl[s][b0] = A0;
  sl[s][b0 + 1] = A1;
  sl[s][b0 + 2] = A2;
  sl[s][b0 + 3] = A3;
  __syncthreads();

  // ---- combine 8 slices (read: lane-consecutive u64 -> 2-way, free) ----
  if (tid < BINS) {
    unsigned long long t = sl[0][tid];
#pragma unroll
    for (int i = 1; i < 8; ++i) t += sl[i][tid];
    __syncthreads();  // all reads done before overwrite
    sl[0][tid] = t;
  } else {
    __syncthreads();
  }
  __syncthreads();

  // ---- inclusive suffix scan over BINS entries (Hillis-Steele) ----
  for (int off = 1; off < BINS; off <<= 1) {
    unsigned long long add = 0;
    if (tid < BINS && tid + off < BINS) add = sl[0][tid + off];
    __syncthreads();
    if (tid < BINS) sl[0][tid] += add;
    __syncthreads();
  }

  float nPos = (float)(unsigned)(sl[0][0] >> 32);  // class total positives
  float acc = 0.f;
  if (tid >= 1 && tid < BINS) {
    unsigned long long suff = sl[0][tid];
    float CP = (float)(unsigned)(suff >> 32);
    float CN = (float)(unsigned)(suff & 0xffffffffull);
    float uni = nPos + CN;
    if (uni > 0.f) acc = 1.0f - (nPos - CP) / uni;
  }

  // ---- block reduce (fixed order) ----
  for (int off = 32; off > 0; off >>= 1) acc += __shfl_down(acc, off, 64);
  int lane = tid & 63, w = tid >> 6;
  if (lane == 0) fsum[w] = acc;
  __syncthreads();
  if (tid == 0) {
    float t = 0.f;
#pragma unroll
    for (int i = 0; i < 16; ++i) t += fsum[i];
    partial[c] = t;
  }
}

// ---------------------------------------------------------------------------
// Phase 3: mean over classes (fixed-order, deterministic).
// ---------------------------------------------------------------------------
__global__ void __launch_bounds__(64) lovasz_final(
    const float* __restrict__ partial, float* __restrict__ out, int n,
    float scale) {
  float acc = 0.f;
  for (int i = threadIdx.x; i < n; i += 64) acc += partial[i];
  for (int off = 32; off > 0; off >>= 1) acc += __shfl_down(acc, off, 64);
  if (threadIdx.x == 0) out[0] = acc * scale;
}

extern "C" void kernel_launch(void* const* d_in, const int* in_sizes, int n_in,
                              void* d_out, int out_size, void* d_ws,
                              size_t ws_size, hipStream_t stream) {
  const float* logits = (const float*)d_in[0];
  const int* labels = (const int*)d_in[1];
  float* out = (float*)d_out;

  const int P = in_sizes[1];  // 8*512*512 = 2,097,152

  // R = copy count = hist grid; 256 = 1 block/CU. Shrink if ws is tiny
  // (R stays a multiple of 8).
  int R = 256;
  while (R > 32 && (size_t)R * NB * 4 + 4096 > ws_size) R >>= 1;
  // ppb multiple of 2048 keeps float2/int2 loads aligned. 8192 at R=256.
  int ppb = ((P + R - 1) / R + 2047) & ~2047;

  char* ws = (char*)d_ws;
  unsigned* copies = (unsigned*)ws;
  float* partial = (float*)(ws + (size_t)R * NB * 4);

  size_t ldsBytes = (size_t)NREP * RSTRIDE * 4;  // ~152 KB -> 1 block/CU

  hist_pf<<<R, 1024, ldsBytes, stream>>>(logits, labels, copies, P, ppb);
  scan19_v2<<<NCLASS, 1024, 0, stream>>>(copies, partial, R);
  lovasz_final<<<1, 64, 0, stream>>>(partial, out, NCLASS,
                                     1.0f / ((float)BINS * (float)NCLASS));
}

// Round 13
// 50.480 us; speedup vs baseline: 1.0732x; 1.0732x over previous
//
#include <hip/hip_runtime.h>
#include <hip/hip_bf16.h>

#define NCLASS 19
#define BINS 256
#define BSHIFT 8
#define NB (NCLASS * BINS)  // 4864 bins
#define NREP 8
#define RPAD 8              // words; shifts each replica's bank phase by 8
#define RSTRIDE (NB + RPAD) // 4872
#define IGNORE_IDX (-100)
#define HW_SHIFT 18  // 512*512 = 2^18 (fixed problem shape)
#define HW_C (1 << HW_SHIFT)

#define UNPACK(v)                                            \
  (((unsigned long long)((v) >> 16) << 32) |                 \
   (unsigned long long)((v) & 0xffffu))

// Load one 2-pixel set: 19 float2 logit streams + int2 labels.
#define LOADSET(V, LB, PIX)                                                  \
  {                                                                          \
    int n_ = (PIX) >> HW_SHIFT;                                              \
    int hw_ = (PIX) & (HW_C - 1);                                            \
    const float* lp_ =                                                       \
        logits + (((size_t)n_ * NCLASS) << HW_SHIFT) + hw_;                  \
    _Pragma("unroll") for (int c_ = 0; c_ < NCLASS; ++c_) {                  \
      float2 q_ = *(const float2*)(lp_ + ((size_t)c_ << HW_SHIFT));          \
      V[c_][0] = q_.x;                                                       \
      V[c_][1] = q_.y;                                                       \
    }                                                                        \
    LB = *(const int2*)(labels + (PIX));                                     \
  }

// Softmax + 2x19 histogram atomics for one 2-pixel set.
#define PROCSET(V, LB)                                                       \
  {                                                                          \
    float m0_ = -3.4e38f, m1_ = -3.4e38f;                                    \
    _Pragma("unroll") for (int c_ = 0; c_ < NCLASS; ++c_) {                  \
      m0_ = fmaxf(m0_, V[c_][0]);                                            \
      m1_ = fmaxf(m1_, V[c_][1]);                                            \
    }                                                                        \
    float s0_ = 0.f, s1_ = 0.f;                                              \
    _Pragma("unroll") for (int c_ = 0; c_ < NCLASS; ++c_) {                  \
      V[c_][0] = __expf(V[c_][0] - m0_); s0_ += V[c_][0];                    \
      V[c_][1] = __expf(V[c_][1] - m1_); s1_ += V[c_][1];                    \
    }                                                                        \
    float i0_ = 1.0f / s0_, i1_ = 1.0f / s1_;                                \
    int l0_ = LB.x, l1_ = LB.y;                                              \
    _Pragma("unroll") for (int c_ = 0; c_ < NCLASS; ++c_) {                  \
      if (l0_ != IGNORE_IDX) {                                               \
        float pr_ = V[c_][0] * i0_;                                          \
        bool pos_ = (c_ == l0_);                                             \
        float e_ = pos_ ? (1.0f - pr_) : pr_;                                \
        int b_ = min(BINS - 1, (int)(e_ * (float)BINS));                     \
        atomicAdd(&sh[rep + (c_ << BSHIFT) + b_], pos_ ? 0x10000u : 1u);     \
      }                                                                      \
      if (l1_ != IGNORE_IDX) {                                               \
        float pr_ = V[c_][1] * i1_;                                          \
        bool pos_ = (c_ == l1_);                                             \
        float e_ = pos_ ? (1.0f - pr_) : pr_;                                \
        int b_ = min(BINS - 1, (int)(e_ * (float)BINS));                     \
        atomicAdd(&sh[rep + (c_ << BSHIFT) + b_], pos_ ? 0x10000u : 1u);     \
      }                                                                      \
    }                                                                        \
  }

// ---------------------------------------------------------------------------
// Phase 1: R7/R8/R11 proven structure; only BINS 512->256 and NREP 4->8
// (atomic density x2, replicas x2 -> conflicts-per-atomic unchanged; replica
// bank phases 0,8,16,24 repeat -> same-bank aliasing max 2-way = free).
// 2 px/thread float2 loads + register double-buffer prefetch (named A/B
// sets), u32-packed pos<<16|neg. Per-replica per-bin count <= 1024 << 65535.
// ---------------------------------------------------------------------------
__global__ void __launch_bounds__(1024, 4) hist_pf(
    const float* __restrict__ logits, const int* __restrict__ labels,
    unsigned* __restrict__ copies, int P, int ppb) {
  extern __shared__ unsigned sh[];  // NREP*RSTRIDE words ~= 152 KB
  for (int i = threadIdx.x; i < NREP * RSTRIDE; i += 1024) sh[i] = 0u;
  __syncthreads();

  const int rep = (threadIdx.x & 7) * RSTRIDE;
  const int STEP = 1024 * 2;
  int p1 = min(P, blockIdx.x * ppb + ppb);
  int p = blockIdx.x * ppb + (int)threadIdx.x * 2;

  float va[NCLASS][2], vb[NCLASS][2];
  int2 la, lb;
  bool has = p < p1;
  if (has) LOADSET(va, la, p);
  while (has) {
    int pn = p + STEP;
    bool hasn = pn < p1;
    if (hasn) LOADSET(vb, lb, pn);  // prefetch next set
    PROCSET(va, la);
    p = pn;
    has = hasn;
    if (!has) break;
    pn = p + STEP;
    hasn = pn < p1;
    if (hasn) LOADSET(va, la, pn);  // prefetch next set
    PROCSET(vb, lb);
    p = pn;
    has = hasn;
  }
  __syncthreads();

  unsigned* dst = copies + (size_t)blockIdx.x * NB;
  for (int i = threadIdx.x; i < NB; i += 1024) {
    unsigned t = 0;
#pragma unroll
    for (int k = 0; k < NREP; ++k) t += sh[k * RSTRIDE + i];
    dst[i] = t;
  }
}

// ---------------------------------------------------------------------------
// Phase 2 (fused tail): one block per class, 1024 threads = 4 quarters x
// 256 bins. R11's proven fold shape: thread (qt,bin) folds R/4 copies with
// 8 independent accumulators (deep pipelining), quarters combined via LDS.
// Then a 256-wide Hillis-Steele inclusive suffix scan and Lovasz J:
// loss_c = (1/BINS)*sum_{b>=1} J_b, (CP,CN) inclusive suffix counts at b;
// nPos = suffix at bin 0. Final mean fused via spin-free ticket: the block
// drawing ticket NCLASS-1 (all others provably done) sums partial[0..18] in
// fixed index order -> deterministic.
// ---------------------------------------------------------------------------
__global__ void __launch_bounds__(1024) scan19_fused(
    const unsigned* __restrict__ copies, float* __restrict__ partial,
    unsigned* __restrict__ counter, float* __restrict__ out, int R) {
  int c = blockIdx.x;
  __shared__ unsigned long long sl[4][BINS];  // 8 KB
  __shared__ float fsum[16];
  int tid = threadIdx.x;
  int bin = tid & (BINS - 1);
  int qt = tid >> BSHIFT;  // quarter 0..3
  int qc = R >> 2;         // copies per quarter (64 at R=256), multiple of 8
  int r0 = qt * qc;

  // ---- fold: 8-way ILP over this quarter's copies ----
  const unsigned* base = copies + (c << BSHIFT) + bin;
  unsigned long long a0 = 0, a1 = 0, a2 = 0, a3 = 0, a4 = 0, a5 = 0, a6 = 0,
                     a7 = 0;
  for (int r = 0; r < qc; r += 8) {
    unsigned v0 = base[(size_t)(r0 + r + 0) * NB];
    unsigned v1 = base[(size_t)(r0 + r + 1) * NB];
    unsigned v2 = base[(size_t)(r0 + r + 2) * NB];
    unsigned v3 = base[(size_t)(r0 + r + 3) * NB];
    unsigned v4 = base[(size_t)(r0 + r + 4) * NB];
    unsigned v5 = base[(size_t)(r0 + r + 5) * NB];
    unsigned v6 = base[(size_t)(r0 + r + 6) * NB];
    unsigned v7 = base[(size_t)(r0 + r + 7) * NB];
    a0 += UNPACK(v0);
    a1 += UNPACK(v1);
    a2 += UNPACK(v2);
    a3 += UNPACK(v3);
    a4 += UNPACK(v4);
    a5 += UNPACK(v5);
    a6 += UNPACK(v6);
    a7 += UNPACK(v7);
  }
  sl[qt][bin] = ((a0 + a1) + (a2 + a3)) + ((a4 + a5) + (a6 + a7));
  __syncthreads();

  // ---- combine quarters ----
  unsigned long long tq = 0;
  if (tid < BINS) tq = (sl[0][tid] + sl[1][tid]) + (sl[2][tid] + sl[3][tid]);
  __syncthreads();
  if (tid < BINS) sl[0][tid] = tq;
  __syncthreads();

  // ---- inclusive suffix scan over BINS entries (Hillis-Steele, 8 rounds) --
  for (int off = 1; off < BINS; off <<= 1) {
    unsigned long long add = 0;
    if (tid < BINS && tid + off < BINS) add = sl[0][tid + off];
    __syncthreads();
    if (tid < BINS) sl[0][tid] += add;
    __syncthreads();
  }

  float nPos = (float)(unsigned)(sl[0][0] >> 32);  // class total positives
  float acc = 0.f;
  if (tid >= 1 && tid < BINS) {
    unsigned long long suff = sl[0][tid];
    float CP = (float)(unsigned)(suff >> 32);
    float CN = (float)(unsigned)(suff & 0xffffffffull);
    float uni = nPos + CN;
    if (uni > 0.f) acc = 1.0f - (nPos - CP) / uni;
  }

  // ---- block reduce (fixed order) ----
  for (int off = 32; off > 0; off >>= 1) acc += __shfl_down(acc, off, 64);
  int lane = tid & 63, w = tid >> 6;
  if (lane == 0) fsum[w] = acc;
  __syncthreads();
  if (tid == 0) {
    float t = 0.f;
#pragma unroll
    for (int i = 0; i < 16; ++i) t += fsum[i];
    partial[c] = t;
    __threadfence();  // release: partial[c] visible before ticket
    unsigned tk = atomicAdd(counter, 1u);
    if (tk == NCLASS - 1) {  // all 18 others already released their partial
      __threadfence();       // acquire
      float m = 0.f;
#pragma unroll
      for (int i = 0; i < NCLASS; ++i)
        m += __hip_atomic_load(&partial[i], __ATOMIC_RELAXED,
                               __HIP_MEMORY_SCOPE_AGENT);
      out[0] = m * (1.0f / ((float)BINS * (float)NCLASS));
    }
  }
}

extern "C" void kernel_launch(void* const* d_in, const int* in_sizes, int n_in,
                              void* d_out, int out_size, void* d_ws,
                              size_t ws_size, hipStream_t stream) {
  const float* logits = (const float*)d_in[0];
  const int* labels = (const int*)d_in[1];
  float* out = (float*)d_out;

  const int P = in_sizes[1];  // 8*512*512 = 2,097,152

  // R = copy count = hist grid; 256 = 1 block/CU. Shrink if ws is tiny
  // (R/4 stays a multiple of 8 down to R=32).
  int R = 256;
  while (R > 32 && (size_t)R * NB * 4 + 4096 > ws_size) R >>= 1;
  // ppb multiple of 2048 keeps float2/int2 loads aligned. 8192 at R=256.
  int ppb = ((P + R - 1) / R + 2047) & ~2047;

  char* ws = (char*)d_ws;
  unsigned* copies = (unsigned*)ws;
  float* partial = (float*)(ws + (size_t)R * NB * 4);
  unsigned* counter = (unsigned*)(partial + 32);

  size_t ldsBytes = (size_t)NREP * RSTRIDE * 4;  // ~152 KB -> 1 block/CU

  // Ticket counter must be zero at the start of EVERY call (graph replays
  // do not re-poison): tiny async memset is capture-safe.
  hipMemsetAsync(counter, 0, sizeof(unsigned), stream);

  hist_pf<<<R, 1024, ldsBytes, stream>>>(logits, labels, copies, P, ppb);
  scan19_fused<<<NCLASS, 1024, 0, stream>>>(copies, partial, counter, out, R);
}

// Round 14
// 48.821 us; speedup vs baseline: 1.1097x; 1.0340x over previous
//
#include <hip/hip_runtime.h>
#include <hip/hip_bf16.h>

#define NCLASS 19
#define BINS 512
#define NB (NCLASS * BINS)  // 9728 bins
#define NREP 4
#define RPAD 8              // words; shifts each replica's bank phase by 8
#define RSTRIDE (NB + RPAD)
#define IGNORE_IDX (-100)
#define HW_SHIFT 18  // 512*512 = 2^18 (fixed problem shape)
#define HW_C (1 << HW_SHIFT)

#define UNPACK(v)                                            \
  (((unsigned long long)((v) >> 16) << 32) |                 \
   (unsigned long long)((v) & 0xffffu))

// Load one 2-pixel set: 19 float2 logit streams + int2 labels.
#define LOADSET(V, LB, PIX)                                                  \
  {                                                                          \
    int n_ = (PIX) >> HW_SHIFT;                                              \
    int hw_ = (PIX) & (HW_C - 1);                                            \
    const float* lp_ =                                                       \
        logits + (((size_t)n_ * NCLASS) << HW_SHIFT) + hw_;                  \
    _Pragma("unroll") for (int c_ = 0; c_ < NCLASS; ++c_) {                  \
      float2 q_ = *(const float2*)(lp_ + ((size_t)c_ << HW_SHIFT));          \
      V[c_][0] = q_.x;                                                       \
      V[c_][1] = q_.y;                                                       \
    }                                                                        \
    LB = *(const int2*)(labels + (PIX));                                     \
  }

// Softmax + 2x19 histogram atomics for one 2-pixel set.
#define PROCSET(V, LB)                                                       \
  {                                                                          \
    float m0_ = -3.4e38f, m1_ = -3.4e38f;                                    \
    _Pragma("unroll") for (int c_ = 0; c_ < NCLASS; ++c_) {                  \
      m0_ = fmaxf(m0_, V[c_][0]);                                            \
      m1_ = fmaxf(m1_, V[c_][1]);                                            \
    }                                                                        \
    float s0_ = 0.f, s1_ = 0.f;                                              \
    _Pragma("unroll") for (int c_ = 0; c_ < NCLASS; ++c_) {                  \
      V[c_][0] = __expf(V[c_][0] - m0_); s0_ += V[c_][0];                    \
      V[c_][1] = __expf(V[c_][1] - m1_); s1_ += V[c_][1];                    \
    }                                                                        \
    float i0_ = 1.0f / s0_, i1_ = 1.0f / s1_;                                \
    int l0_ = LB.x, l1_ = LB.y;                                              \
    _Pragma("unroll") for (int c_ = 0; c_ < NCLASS; ++c_) {                  \
      if (l0_ != IGNORE_IDX) {                                               \
        float pr_ = V[c_][0] * i0_;                                          \
        bool pos_ = (c_ == l0_);                                             \
        float e_ = pos_ ? (1.0f - pr_) : pr_;                                \
        int b_ = min(BINS - 1, (int)(e_ * (float)BINS));                     \
        atomicAdd(&sh[rep + (c_ << 9) + b_], pos_ ? 0x10000u : 1u);          \
      }                                                                      \
      if (l1_ != IGNORE_IDX) {                                               \
        float pr_ = V[c_][1] * i1_;                                          \
        bool pos_ = (c_ == l1_);                                             \
        float e_ = pos_ ? (1.0f - pr_) : pr_;                                \
        int b_ = min(BINS - 1, (int)(e_ * (float)BINS));                     \
        atomicAdd(&sh[rep + (c_ << 9) + b_], pos_ ? 0x10000u : 1u);          \
      }                                                                      \
    }                                                                        \
  }

// ---------------------------------------------------------------------------
// Phase 1 (proven R11 core, VERBATIM except the 1-store counter zeroing):
// 2 px/thread float2 loads, 4-way lane-replicated LDS histogram (u32-packed
// pos<<16|neg), register double-buffer prefetch with named A/B sets.
// Block 0 / thread 0 zeroes the scan ticket counter; the kernel boundary
// makes it visible to scan19_fused (deterministic, poison-safe, and saves a
// separate memset dispatch).
// ---------------------------------------------------------------------------
__global__ void __launch_bounds__(1024, 4) hist_pf(
    const float* __restrict__ logits, const int* __restrict__ labels,
    unsigned* __restrict__ copies, unsigned* __restrict__ counter, int P,
    int ppb) {
  extern __shared__ unsigned sh[];  // NREP*RSTRIDE words ~= 152 KB
  if (blockIdx.x == 0 && threadIdx.x == 0) *counter = 0u;
  for (int i = threadIdx.x; i < NREP * RSTRIDE; i += 1024) sh[i] = 0u;
  __syncthreads();

  const int rep = (threadIdx.x & 3) * RSTRIDE;
  const int STEP = 1024 * 2;
  int p1 = min(P, blockIdx.x * ppb + ppb);
  int p = blockIdx.x * ppb + (int)threadIdx.x * 2;

  float va[NCLASS][2], vb[NCLASS][2];
  int2 la, lb;
  bool has = p < p1;
  if (has) LOADSET(va, la, p);
  while (has) {
    int pn = p + STEP;
    bool hasn = pn < p1;
    if (hasn) LOADSET(vb, lb, pn);  // prefetch next set
    PROCSET(va, la);
    p = pn;
    has = hasn;
    if (!has) break;
    pn = p + STEP;
    hasn = pn < p1;
    if (hasn) LOADSET(va, la, pn);  // prefetch next set
    PROCSET(vb, lb);
    p = pn;
    has = hasn;
  }
  __syncthreads();

  unsigned* dst = copies + (size_t)blockIdx.x * NB;
  for (int i = threadIdx.x; i < NB; i += 1024)
    dst[i] =
        sh[i] + sh[RSTRIDE + i] + sh[2 * RSTRIDE + i] + sh[3 * RSTRIDE + i];
}

// ---------------------------------------------------------------------------
// Phase 2 (fused tail): one block per class, 1024 threads = 2 halves x 512
// bins — R11's proven fold shape: each thread folds R/2 copies for its bin
// with 8 INDEPENDENT accumulators (deep pipelining), halves combined via
// LDS. Then the 512-wide Hillis-Steele inclusive suffix scan and Lovasz J:
// loss_c = (1/BINS)*sum_{b>=1} J_b, (CP,CN) inclusive suffix counts at b;
// nPos = suffix at bin 0 = class total. Final mean fused via the proven
// R13 spin-free ticket: the block drawing ticket NCLASS-1 (all others
// provably done) sums partial[0..18] in fixed index order -> deterministic.
// ---------------------------------------------------------------------------
__global__ void __launch_bounds__(1024) scan19_fused(
    const unsigned* __restrict__ copies, float* __restrict__ partial,
    unsigned* __restrict__ counter, float* __restrict__ out, int R) {
  int c = blockIdx.x;
  __shared__ unsigned long long binsA[BINS];  // 4 KB (also scan array)
  __shared__ unsigned long long binsB[BINS];  // 4 KB
  __shared__ float fsum[16];
  int tid = threadIdx.x;
  int bin = tid & (BINS - 1);
  int half = tid >> 9;  // 0 or 1

  // ---- fold: each thread sums R/2 copies for its bin, 8-way ILP ----
  int hc = R >> 1;  // copies per half (128 at R=256), multiple of 8
  int r0 = half * hc;
  const unsigned* base = copies + (c << 9) + bin;
  unsigned long long a0 = 0, a1 = 0, a2 = 0, a3 = 0, a4 = 0, a5 = 0, a6 = 0,
                     a7 = 0;
  for (int r = 0; r < hc; r += 8) {
    unsigned v0 = base[(size_t)(r0 + r + 0) * NB];
    unsigned v1 = base[(size_t)(r0 + r + 1) * NB];
    unsigned v2 = base[(size_t)(r0 + r + 2) * NB];
    unsigned v3 = base[(size_t)(r0 + r + 3) * NB];
    unsigned v4 = base[(size_t)(r0 + r + 4) * NB];
    unsigned v5 = base[(size_t)(r0 + r + 5) * NB];
    unsigned v6 = base[(size_t)(r0 + r + 6) * NB];
    unsigned v7 = base[(size_t)(r0 + r + 7) * NB];
    a0 += UNPACK(v0);
    a1 += UNPACK(v1);
    a2 += UNPACK(v2);
    a3 += UNPACK(v3);
    a4 += UNPACK(v4);
    a5 += UNPACK(v5);
    a6 += UNPACK(v6);
    a7 += UNPACK(v7);
  }
  unsigned long long a = ((a0 + a1) + (a2 + a3)) + ((a4 + a5) + (a6 + a7));
  if (half == 0)
    binsA[bin] = a;
  else
    binsB[bin] = a;
  __syncthreads();
  if (half == 0) binsA[bin] += binsB[bin];
  __syncthreads();

  // ---- inclusive suffix scan over BINS entries (Hillis-Steele, 9 rounds) --
  for (int off = 1; off < BINS; off <<= 1) {
    unsigned long long add = 0;
    if (half == 0 && bin + off < BINS) add = binsA[bin + off];
    __syncthreads();
    if (half == 0) binsA[bin] += add;
    __syncthreads();
  }

  float nPos = (float)(unsigned)(binsA[0] >> 32);  // class total positives
  float acc = 0.f;
  if (half == 0 && bin >= 1) {
    unsigned long long suff = binsA[bin];
    float CP = (float)(unsigned)(suff >> 32);
    float CN = (float)(unsigned)(suff & 0xffffffffull);
    float uni = nPos + CN;
    if (uni > 0.f) acc = 1.0f - (nPos - CP) / uni;
  }

  // ---- block reduce (fixed order) + ticket-fused final mean ----
  for (int off = 32; off > 0; off >>= 1) acc += __shfl_down(acc, off, 64);
  int lane = tid & 63, w = tid >> 6;
  if (lane == 0) fsum[w] = acc;
  __syncthreads();
  if (tid == 0) {
    float t = 0.f;
#pragma unroll
    for (int i = 0; i < 16; ++i) t += fsum[i];
    partial[c] = t;
    __threadfence();  // release: partial[c] visible before ticket
    unsigned tk = atomicAdd(counter, 1u);
    if (tk == NCLASS - 1) {  // all 18 others already released their partial
      __threadfence();       // acquire
      float m = 0.f;
#pragma unroll
      for (int i = 0; i < NCLASS; ++i)
        m += __hip_atomic_load(&partial[i], __ATOMIC_RELAXED,
                               __HIP_MEMORY_SCOPE_AGENT);
      out[0] = m * (1.0f / ((float)BINS * (float)NCLASS));
    }
  }
}

extern "C" void kernel_launch(void* const* d_in, const int* in_sizes, int n_in,
                              void* d_out, int out_size, void* d_ws,
                              size_t ws_size, hipStream_t stream) {
  const float* logits = (const float*)d_in[0];
  const int* labels = (const int*)d_in[1];
  float* out = (float*)d_out;

  const int P = in_sizes[1];  // 8*512*512 = 2,097,152

  // R = copy count = hist grid; 256 = 1 block/CU. Shrink if ws is tiny
  // (R/2 stays a multiple of 8 down to R=16).
  int R = 256;
  while (R > 32 && (size_t)R * NB * 4 + 4096 > ws_size) R >>= 1;
  // ppb multiple of 2048 keeps float2/int2 loads aligned. 8192 at R=256.
  int ppb = ((P + R - 1) / R + 2047) & ~2047;

  char* ws = (char*)d_ws;
  unsigned* copies = (unsigned*)ws;
  float* partial = (float*)(ws + (size_t)R * NB * 4);
  unsigned* counter = (unsigned*)(partial + 32);

  size_t ldsBytes = (size_t)NREP * RSTRIDE * 4;  // ~152 KB -> 1 block/CU

  hist_pf<<<R, 1024, ldsBytes, stream>>>(logits, labels, copies, counter, P,
                                         ppb);
  scan19_fused<<<NCLASS, 1024, 0, stream>>>(copies, partial, counter, out, R);
}